// Round 4
// baseline (505.543 us; speedup 1.0000x reference)
//
#include <hip/hip_runtime.h>

#define NFOLDS 12
#define EPS 1e-8f
#define BATCH 2048
#define IN_DIM 128
#define UNITS 256
#define RB 4
#define LOG2E 1.44269504088896340736f
#define VCLAMP 4.5f

#if __has_builtin(__builtin_amdgcn_rcpf)
#define RCPF(x) __builtin_amdgcn_rcpf(x)
#else
#define RCPF(x) (1.0f / (x))
#endif

typedef float f2 __attribute__((ext_vector_type(2)));

__device__ __forceinline__ f2 pk_fma(f2 a, f2 b, f2 c) {
    f2 d;
    asm("v_pk_fma_f32 %0, %1, %2, %3" : "=v"(d) : "v"(a), "v"(b), "v"(c));
    return d;
}
__device__ __forceinline__ f2 pk_add(f2 a, f2 b) {
    f2 d;
    asm("v_pk_add_f32 %0, %1, %2" : "=v"(d) : "v"(a), "v"(b));
    return d;
}

// Schraudolph magic: z = t + C rounds t to nearest int n (RTNE) in the
// mantissa; C = 1.5*2^23 + 127 folds the exponent bias so that
// bitcast(z_bits << 23) == 2^n as float (valid for |t| <= 126; here |t|<=62).
#define MAGIC_C 12583039.0f   // 1.5*2^23 + 127

// Taylor deg-4 for 2^f on [-0.5, 0.5], rel err ~4.2e-5
#define EC1 0.6931471805599453f
#define EC2 0.2402265069591007f
#define EC3 0.0555041086648216f
#define EC4 0.0096181291076285f

struct SigK {
    f2 C2, negC2, neg1, one2, c1, c2, c3, c4;
};

// One synapse pair, no transcendental exp:
//   t  = qa.xy * v + qa.zw          (t = -A(v-mu) in log2 units)
//   2^t = poly(f) * 2^n  via magic round
//   A  = 1 + 2^t ; g_i = 1/A_i via shared reciprocal
//   red += qb.xy * g ; num += qb.zw * g
__device__ __forceinline__ void syn_pair(const float4 qa, const float4 qb,
                                         const f2 v2, const SigK& K,
                                         f2& red, f2& num) {
    f2 t = pk_fma(f2{qa.x, qa.y}, v2, f2{qa.z, qa.w});
    f2 z = pk_add(t, K.C2);        // n = round(t) encoded in mantissa
    f2 n = pk_add(z, K.negC2);     // n as float (exact)
    f2 f = pk_fma(n, K.neg1, t);   // f = t - n in [-0.5, 0.5] (exact)
    f2 p = pk_fma(K.c4, f, K.c3);
    p = pk_fma(p, f, K.c2);
    p = pk_fma(p, f, K.c1);
    p = pk_fma(p, f, K.one2);      // p = 2^f
    f2 s;
    s.x = __uint_as_float(__float_as_uint(z.x) << 23);   // 2^n
    s.y = __uint_as_float(__float_as_uint(z.y) << 23);
    f2 A = pk_fma(p, s, K.one2);   // A = 1 + 2^t
    float P = A.x * A.y;
    float R = RCPF(P);             // the only transcendental
    f2 g;
    g.x = R * A.y;                 // 1/A0
    g.y = R * A.x;                 // 1/A1
    red = pk_fma(f2{qb.x, qb.y}, g, red);
    num = pk_fma(f2{qb.z, qb.w}, g, num);
}

// Pair-packed params: for row-pair p (rows 2p,2p+1), col u:
//   outA[p*cols+u] = {-A0, -A1, A0*mu0, A1*mu1}   (A = sigma*log2e)
//   outB[p*cols+u] = {W0, W1, W0*erev0, W1*erev1}
__global__ void prep_pair_kernel(const float* __restrict__ mu,
                                 const float* __restrict__ sigma,
                                 const float* __restrict__ W,
                                 const float* __restrict__ erev,
                                 float4* __restrict__ outA,
                                 float4* __restrict__ outB, int n) {
    int i = blockIdx.x * blockDim.x + threadIdx.x;  // i = p*UNITS + u
    if (i < n) {
        int p = i >> 8;
        int u = i & (UNITS - 1);
        int i0 = (2 * p) * UNITS + u;
        int i1 = i0 + UNITS;
        float A0 = sigma[i0] * LOG2E, A1 = sigma[i1] * LOG2E;
        outA[i] = make_float4(-A0, -A1, A0 * mu[i0], A1 * mu[i1]);
        float w0 = W[i0], w1 = W[i1];
        outB[i] = make_float4(w0, w1, w0 * erev[i0], w1 * erev[i1]);
    }
}

// Block: 512 threads = (u: 0..255) x (h: reduction half 0..1). RB=4 rows.
__global__ __launch_bounds__(512, 4) void ltc_kernel(
    const float4* __restrict__ rpA,   // [UNITS/2][UNITS] recurrent pair params
    const float4* __restrict__ rpB,
    const float4* __restrict__ spA,   // [IN_DIM/2][UNITS] sensory pair params
    const float4* __restrict__ spB,
    const float* __restrict__ inputs, // [BATCH][IN_DIM]
    const float* __restrict__ state,  // [BATCH][UNITS]
    const float* __restrict__ vleak,
    const float* __restrict__ gleak,
    const float* __restrict__ cm_t,
    float* __restrict__ out)          // [BATCH][UNITS]
{
    const int tid = threadIdx.x;
    const int u = tid & (UNITS - 1);
    const int h = tid >> 8;
    const int b0 = blockIdx.x * RB;

    SigK K;
    K.C2   = f2{MAGIC_C, MAGIC_C};
    K.negC2 = f2{-MAGIC_C, -MAGIC_C};
    K.neg1 = f2{-1.0f, -1.0f};
    K.one2 = f2{1.0f, 1.0f};
    K.c1 = f2{EC1, EC1};
    K.c2 = f2{EC2, EC2};
    K.c3 = f2{EC3, EC3};
    K.c4 = f2{EC4, EC4};

    __shared__ __align__(16) float v_sh[RB][UNITS];
    __shared__ __align__(16) float in_sh[RB][IN_DIM];
    __shared__ float nb_sh[RB][UNITS];   // glvl + snum
    __shared__ float db_sh[RB][UNITS];   // cm + gl + sden + EPS
    __shared__ float cm_sh[UNITS];
    __shared__ float pred[2][RB][UNITS];
    __shared__ float pnum[2][RB][UNITS];

    // ---- stage rows. v_sh holds CLAMPED v (synapse input only; |t|<=62
    //      guarantee for the magic-exp). Unclamped v kept in registers for
    //      the cm*v term: thread (u,h) owns rows rb = h and h+2. ----
    if (h == 0) {
        #pragma unroll
        for (int rb = 0; rb < RB; ++rb) {
            float s = state[(b0 + rb) * UNITS + u];
            v_sh[rb][u] = fminf(fmaxf(s, -VCLAMP), VCLAMP);
        }
        cm_sh[u] = cm_t[u];
    } else {
        #pragma unroll
        for (int k = u; k < RB * IN_DIM; k += UNITS) {
            int rb = k >> 7;
            int i  = k & (IN_DIM - 1);
            float x = inputs[(b0 + rb) * IN_DIM + i];
            in_sh[rb][i] = fminf(fmaxf(x, -VCLAMP), VCLAMP);
        }
    }
    // unclamped v for this thread's two rows
    float vfull[2];
    #pragma unroll
    for (int k = 0; k < 2; ++k)
        vfull[k] = state[(b0 + h + 2 * k) * UNITS + u];
    __syncthreads();

    // ---- sensory path: half h sums i in [h*64, h*64+64) = 32 pairs ----
    {
        f2 sden[RB] = {{0.f,0.f},{0.f,0.f},{0.f,0.f},{0.f,0.f}};
        f2 snum[RB] = {{0.f,0.f},{0.f,0.f},{0.f,0.f},{0.f,0.f}};
        const int ibase = h * (IN_DIM / 2);
        for (int ic = 0; ic < IN_DIM / 2; ic += 4) {
            const int i = ibase + ic;
            const int pr = i >> 1;
            float4 qa0 = spA[(pr + 0) * UNITS + u];
            float4 qb0 = spB[(pr + 0) * UNITS + u];
            float4 qa1 = spA[(pr + 1) * UNITS + u];
            float4 qb1 = spB[(pr + 1) * UNITS + u];
            #pragma unroll
            for (int rb = 0; rb < RB; ++rb) {
                float4 x4 = *reinterpret_cast<const float4*>(&in_sh[rb][i]);
                syn_pair(qa0, qb0, f2{x4.x, x4.y}, K, sden[rb], snum[rb]);
                syn_pair(qa1, qb1, f2{x4.z, x4.w}, K, sden[rb], snum[rb]);
            }
        }
        #pragma unroll
        for (int rb = 0; rb < RB; ++rb) {
            pred[h][rb][u] = sden[rb].x + sden[rb].y;
            pnum[h][rb][u] = snum[rb].x + snum[rb].y;
        }
    }
    __syncthreads();

    // combine sensory partials into per-(rb,u) bases
    #pragma unroll
    for (int k = 0; k < 2; ++k) {
        const int rb = h + 2 * k;
        float gl = gleak[u];
        float sd = pred[0][rb][u] + pred[1][rb][u];
        float sn = pnum[0][rb][u] + pnum[1][rb][u];
        db_sh[rb][u] = cm_sh[u] + gl + sd + EPS;
        nb_sh[rb][u] = fmaf(gl, vleak[u], sn);
    }
    __syncthreads();

    // ---- 12 folds: half h reduces j in [h*128, h*128+128) = 64 pairs ----
    for (int f = 0; f < NFOLDS; ++f) {
        f2 wred[RB] = {{0.f,0.f},{0.f,0.f},{0.f,0.f},{0.f,0.f}};
        f2 wnum[RB] = {{0.f,0.f},{0.f,0.f},{0.f,0.f},{0.f,0.f}};
        const int jbase = h * (UNITS / 2);
        for (int jc = 0; jc < UNITS / 2; jc += 4) {
            const int j = jbase + jc;
            const int pr = j >> 1;
            float4 qa0 = rpA[(pr + 0) * UNITS + u];
            float4 qb0 = rpB[(pr + 0) * UNITS + u];
            float4 qa1 = rpA[(pr + 1) * UNITS + u];
            float4 qb1 = rpB[(pr + 1) * UNITS + u];
            #pragma unroll
            for (int rb = 0; rb < RB; ++rb) {
                float4 v4 = *reinterpret_cast<const float4*>(&v_sh[rb][j]);
                syn_pair(qa0, qb0, f2{v4.x, v4.y}, K, wred[rb], wnum[rb]);
                syn_pair(qa1, qb1, f2{v4.z, v4.w}, K, wred[rb], wnum[rb]);
            }
        }
        #pragma unroll
        for (int rb = 0; rb < RB; ++rb) {
            pred[h][rb][u] = wred[rb].x + wred[rb].y;
            pnum[h][rb][u] = wnum[rb].x + wnum[rb].y;
        }
        __syncthreads();

        #pragma unroll
        for (int k = 0; k < 2; ++k) {
            const int rb = h + 2 * k;
            float wr = pred[0][rb][u] + pred[1][rb][u];
            float wn = pnum[0][rb][u] + pnum[1][rb][u];
            float num = fmaf(cm_sh[u], vfull[k], nb_sh[rb][u]) + wn;
            float den = db_sh[rb][u] + wr;
            float vn = num * RCPF(den);
            vfull[k] = vn;                                   // exact v for cm*v
            v_sh[rb][u] = fminf(fmaxf(vn, -VCLAMP), VCLAMP); // synapse input
            if (f == NFOLDS - 1)
                out[(b0 + rb) * UNITS + u] = vn;
        }
        __syncthreads();
    }
}

extern "C" void kernel_launch(void* const* d_in, const int* in_sizes, int n_in,
                              void* d_out, int out_size, void* d_ws, size_t ws_size,
                              hipStream_t stream) {
    const float* inputs       = (const float*)d_in[0];
    const float* state        = (const float*)d_in[1];
    const float* sensory_mu   = (const float*)d_in[2];
    const float* sensory_sig  = (const float*)d_in[3];
    const float* sensory_W    = (const float*)d_in[4];
    const float* sensory_erev = (const float*)d_in[5];
    const float* mu           = (const float*)d_in[6];
    const float* sigma        = (const float*)d_in[7];
    const float* W            = (const float*)d_in[8];
    const float* erev         = (const float*)d_in[9];
    const float* vleak        = (const float*)d_in[10];
    const float* gleak        = (const float*)d_in[11];
    const float* cm_t         = (const float*)d_in[12];
    float* out = (float*)d_out;

    // workspace: rpA | rpB | spA | spB  (pair-packed float4 arrays)
    float4* rpA = (float4*)d_ws;
    float4* rpB = rpA + (UNITS / 2) * UNITS;
    float4* spA = rpB + (UNITS / 2) * UNITS;
    float4* spB = spA + (IN_DIM / 2) * UNITS;

    int n_rec = (UNITS / 2) * UNITS;   // 32768 pair-slots
    int n_sen = (IN_DIM / 2) * UNITS;  // 16384
    prep_pair_kernel<<<(n_rec + 255) / 256, 256, 0, stream>>>(
        mu, sigma, W, erev, rpA, rpB, n_rec);
    prep_pair_kernel<<<(n_sen + 255) / 256, 256, 0, stream>>>(
        sensory_mu, sensory_sig, sensory_W, sensory_erev, spA, spB, n_sen);

    ltc_kernel<<<BATCH / RB, 512, 0, stream>>>(rpA, rpB, spA, spB, inputs, state,
                                               vleak, gleak, cm_t, out);
}